// Round 1
// baseline (33441.174 us; speedup 1.0000x reference)
//
#include <hip/hip_runtime.h>
#include <hip/hip_bf16.h>
#include <math.h>

#define BATCH 32
#define DEPTH 12
#define DIM 768
#define HEADS 12
#define MLP_DIM 3072
#define PATCH 16
#define GRID 14
#define NCLS 1000
#define N_TOK 197      // GRID*GRID + 1
#define HD 64          // DIM / HEADS
#define NPATCH 196

// ---------------------------------------------------------------------------
// im2col: x (B,3,224,224) -> patches (B*196, 768), elem e = c*256 + py*16 + px
// ---------------------------------------------------------------------------
__global__ __launch_bounds__(256) void im2col_kernel(const float* __restrict__ x,
                                                     float* __restrict__ patches) {
    int idx = blockIdx.x * 256 + threadIdx.x;
    const int total = BATCH * NPATCH * DIM;
    if (idx >= total) return;
    int e = idx % DIM;
    int n = (idx / DIM) % NPATCH;
    int b = idx / (DIM * NPATCH);
    int c = e / (PATCH * PATCH);
    int r = e % (PATCH * PATCH);
    int py = r / PATCH, px = r % PATCH;
    int gy = n / GRID, gx = n % GRID;
    size_t xi = (((size_t)(b * 3 + c) * 224 + gy * PATCH + py)) * 224 + gx * PATCH + px;
    patches[idx] = x[xi];
}

// ---------------------------------------------------------------------------
// assemble: t[b,0,:] = cls + pos[0]; t[b,n,:] = patchout[b,n-1,:] + pos[n]
// ---------------------------------------------------------------------------
__global__ __launch_bounds__(256) void assemble_kernel(const float* __restrict__ patchout,
                                                       const float* __restrict__ cls,
                                                       const float* __restrict__ pos,
                                                       float* __restrict__ t) {
    int idx = blockIdx.x * 256 + threadIdx.x;
    const int total = BATCH * N_TOK * DIM;
    if (idx >= total) return;
    int d = idx % DIM;
    int n = (idx / DIM) % N_TOK;
    int b = idx / (DIM * N_TOK);
    float v = (n == 0) ? cls[d] : patchout[((size_t)b * NPATCH + (n - 1)) * DIM + d];
    t[idx] = v + pos[n * DIM + d];
}

// ---------------------------------------------------------------------------
// LayerNorm: one block per row, 256 threads, DIM=768 = 3*256.
// in_stride/out_stride in elements.
// ---------------------------------------------------------------------------
__global__ __launch_bounds__(256) void ln_kernel(const float* __restrict__ x,
                                                 const float* __restrict__ g,
                                                 const float* __restrict__ bta,
                                                 float* __restrict__ out,
                                                 int in_stride, int out_stride) {
    int row = blockIdx.x;
    const float* xr = x + (size_t)row * in_stride;
    float* orow = out + (size_t)row * out_stride;
    int tid = threadIdx.x;

    float v0 = xr[tid], v1 = xr[tid + 256], v2 = xr[tid + 512];
    float s = v0 + v1 + v2;
    float s2 = v0 * v0 + v1 * v1 + v2 * v2;

    __shared__ float red[256];
    __shared__ float red2[256];
    red[tid] = s; red2[tid] = s2;
    __syncthreads();
    for (int st = 128; st > 0; st >>= 1) {
        if (tid < st) { red[tid] += red[tid + st]; red2[tid] += red2[tid + st]; }
        __syncthreads();
    }
    float mean = red[0] * (1.0f / DIM);
    float var = red2[0] * (1.0f / DIM) - mean * mean;
    float inv = rsqrtf(var + 1e-6f);

    orow[tid]       = (v0 - mean) * inv * g[tid]       + bta[tid];
    orow[tid + 256] = (v1 - mean) * inv * g[tid + 256] + bta[tid + 256];
    orow[tid + 512] = (v2 - mean) * inv * g[tid + 512] + bta[tid + 512];
}

// ---------------------------------------------------------------------------
// Generic fp32 GEMM: C[m,n] = (RES? res[m,n]:0) + epi(A[m,:]@W[:,n] + bias[n])
// 64x64 tile, BK=16, 256 threads, 4x4 per thread. K must be %16==0.
// ---------------------------------------------------------------------------
template <int BIAS, int DO_GELU, int RES>
__global__ __launch_bounds__(256) void gemm_kernel(const float* __restrict__ A, int lda,
                                                   const float* __restrict__ W,
                                                   const float* __restrict__ bias,
                                                   const float* __restrict__ res,
                                                   float* __restrict__ C, int ldc,
                                                   int M, int Nc, int K) {
    __shared__ float As[16][65];
    __shared__ float Ws[16][65];

    int block_row = blockIdx.y * 64;
    int block_col = blockIdx.x * 64;
    int tid = threadIdx.x;
    int ty = tid / 16, tx = tid % 16;

    float acc[4][4] = {};

    int a_m = tid / 4;         // 0..63
    int a_k = (tid % 4) * 4;   // 0,4,8,12
    int w_k = tid / 16;        // 0..15
    int w_n = (tid % 16) * 4;  // 0..60

    for (int k0 = 0; k0 < K; k0 += 16) {
        int gm = block_row + a_m;
        const float* arow = A + (size_t)gm * lda + k0 + a_k;
#pragma unroll
        for (int i = 0; i < 4; i++)
            As[a_k + i][a_m] = (gm < M) ? arow[i] : 0.0f;

        int gn = block_col + w_n;
        const float* wrow = W + (size_t)(k0 + w_k) * Nc + gn;
#pragma unroll
        for (int j = 0; j < 4; j++)
            Ws[w_k][w_n + j] = (gn + j < Nc) ? wrow[j] : 0.0f;

        __syncthreads();
#pragma unroll
        for (int kk = 0; kk < 16; kk++) {
            float a[4], w[4];
#pragma unroll
            for (int i = 0; i < 4; i++) a[i] = As[kk][ty * 4 + i];
#pragma unroll
            for (int j = 0; j < 4; j++) w[j] = Ws[kk][tx * 4 + j];
#pragma unroll
            for (int i = 0; i < 4; i++)
#pragma unroll
                for (int j = 0; j < 4; j++) acc[i][j] += a[i] * w[j];
        }
        __syncthreads();
    }

#pragma unroll
    for (int i = 0; i < 4; i++) {
        int gm = block_row + ty * 4 + i;
        if (gm >= M) continue;
#pragma unroll
        for (int j = 0; j < 4; j++) {
            int gn = block_col + tx * 4 + j;
            if (gn >= Nc) continue;
            float v = acc[i][j];
            if (BIAS) v += bias[gn];
            if (DO_GELU) v = 0.5f * v * (1.0f + erff(v * 0.70710678118654752f));
            if (RES) v += res[(size_t)gm * ldc + gn];
            C[(size_t)gm * ldc + gn] = v;
        }
    }
}

// ---------------------------------------------------------------------------
// Attention: one block per (query i, head h, batch b). 256 threads.
// qkv layout: [(b*N + n)*3 + which][DIM], col = h*HD + d.
// attn = softmax(q.k * scale * mask[i,j]); o[b,i,h*HD+d] = sum_j p*v
// ---------------------------------------------------------------------------
__global__ __launch_bounds__(256) void attn_kernel(const float* __restrict__ qkv,
                                                   const float* __restrict__ mask,
                                                   float* __restrict__ o) {
    int i = blockIdx.x;
    int h = blockIdx.y;
    int b = blockIdx.z;
    int tid = threadIdx.x;
    const float scale = 0.125f;  // 64^-0.5

    __shared__ float q[HD];
    __shared__ float p[N_TOK];
    __shared__ float red[256];

    if (tid < HD)
        q[tid] = qkv[((size_t)(b * N_TOK + i) * 3 + 0) * DIM + h * HD + tid];
    __syncthreads();

    for (int j = tid; j < N_TOK; j += 256) {
        const float* krow = qkv + ((size_t)(b * N_TOK + j) * 3 + 1) * DIM + h * HD;
        float s = 0.0f;
#pragma unroll
        for (int d = 0; d < HD; d++) s += q[d] * krow[d];
        p[j] = s * scale * mask[i * N_TOK + j];
    }
    __syncthreads();

    // max
    float m = -INFINITY;
    for (int j = tid; j < N_TOK; j += 256) m = fmaxf(m, p[j]);
    red[tid] = m;
    __syncthreads();
    for (int st = 128; st > 0; st >>= 1) {
        if (tid < st) red[tid] = fmaxf(red[tid], red[tid + st]);
        __syncthreads();
    }
    m = red[0];
    __syncthreads();

    // exp & sum
    float sum = 0.0f;
    for (int j = tid; j < N_TOK; j += 256) {
        float e = __expf(p[j] - m);
        p[j] = e;
        sum += e;
    }
    red[tid] = sum;
    __syncthreads();
    for (int st = 128; st > 0; st >>= 1) {
        if (tid < st) red[tid] += red[tid + st];
        __syncthreads();
    }
    float inv = 1.0f / red[0];
    __syncthreads();

    // o: 4 groups of 64 lanes; lane d accumulates strided j
    int d = tid & 63;
    int grp = tid >> 6;
    float acc = 0.0f;
    for (int j = grp; j < N_TOK; j += 4)
        acc += p[j] * qkv[((size_t)(b * N_TOK + j) * 3 + 2) * DIM + h * HD + d];
    red[tid] = acc;
    __syncthreads();
    if (tid < 64) {
        float r = red[tid] + red[tid + 64] + red[tid + 128] + red[tid + 192];
        o[((size_t)(b * N_TOK + i)) * DIM + h * HD + tid] = r * inv;
    }
}

// ---------------------------------------------------------------------------
extern "C" void kernel_launch(void* const* d_in, const int* in_sizes, int n_in,
                              void* d_out, int out_size, void* d_ws, size_t ws_size,
                              hipStream_t stream) {
    const float* x       = (const float*)d_in[0];
    const float* cp_mask = (const float*)d_in[1];
    const float* patch_w = (const float*)d_in[2];
    const float* patch_b = (const float*)d_in[3];
    const float* cls_tok = (const float*)d_in[4];
    const float* pos_emb = (const float*)d_in[5];
    const float* ln1_g   = (const float*)d_in[6];
    const float* ln1_b   = (const float*)d_in[7];
    const float* qkv_w   = (const float*)d_in[8];
    const float* qkv_b   = (const float*)d_in[9];
    const float* proj_w  = (const float*)d_in[10];
    const float* proj_b  = (const float*)d_in[11];
    const float* ln2_g   = (const float*)d_in[12];
    const float* ln2_b   = (const float*)d_in[13];
    const float* fc1_w   = (const float*)d_in[14];
    const float* fc1_b   = (const float*)d_in[15];
    const float* fc2_w   = (const float*)d_in[16];
    const float* fc2_b   = (const float*)d_in[17];
    const float* normf_g = (const float*)d_in[18];
    const float* normf_b = (const float*)d_in[19];
    const float* head_w  = (const float*)d_in[20];
    const float* head_b  = (const float*)d_in[21];
    float* out = (float*)d_out;

    const size_t TOK = (size_t)BATCH * N_TOK;           // 6304 rows
    float* ws = (float*)d_ws;
    float* t      = ws;                                  // TOK*DIM
    float* h      = t + TOK * DIM;                       // TOK*DIM
    float* qkv    = h + TOK * DIM;                       // TOK*3*DIM
    float* o      = qkv + TOK * 3 * DIM;                 // TOK*DIM
    float* hidden = o + TOK * DIM;                       // TOK*MLP_DIM
    float* pooled = hidden + TOK * MLP_DIM;              // BATCH*DIM
    float* patches  = hidden;                            // reuse (pre-loop only)
    float* patchout = qkv;                               // reuse (pre-loop only)

    const int M = (int)TOK;  // 6304

    // ---- patch embedding ----
    {
        int total = BATCH * NPATCH * DIM;
        im2col_kernel<<<(total + 255) / 256, 256, 0, stream>>>(x, patches);
        dim3 g((DIM + 63) / 64, (BATCH * NPATCH + 63) / 64);
        gemm_kernel<1, 0, 0><<<g, 256, 0, stream>>>(patches, DIM, patch_w, patch_b,
                                                    nullptr, patchout, DIM,
                                                    BATCH * NPATCH, DIM, DIM);
        int total2 = BATCH * N_TOK * DIM;
        assemble_kernel<<<(total2 + 255) / 256, 256, 0, stream>>>(patchout, cls_tok, pos_emb, t);
    }

    // ---- transformer layers ----
    for (int l = 0; l < DEPTH; l++) {
        ln_kernel<<<M, 256, 0, stream>>>(t, ln1_g + l * DIM, ln1_b + l * DIM, h, DIM, DIM);

        {
            dim3 g((3 * DIM + 63) / 64, (M + 63) / 64);
            gemm_kernel<1, 0, 0><<<g, 256, 0, stream>>>(
                h, DIM, qkv_w + (size_t)l * DIM * 3 * DIM, qkv_b + (size_t)l * 3 * DIM,
                nullptr, qkv, 3 * DIM, M, 3 * DIM, DIM);
        }

        {
            dim3 g(N_TOK, HEADS, BATCH);
            attn_kernel<<<g, 256, 0, stream>>>(qkv, cp_mask, o);
        }

        {
            dim3 g((DIM + 63) / 64, (M + 63) / 64);
            gemm_kernel<1, 0, 1><<<g, 256, 0, stream>>>(
                o, DIM, proj_w + (size_t)l * DIM * DIM, proj_b + (size_t)l * DIM,
                t, t, DIM, M, DIM, DIM);
        }

        ln_kernel<<<M, 256, 0, stream>>>(t, ln2_g + l * DIM, ln2_b + l * DIM, h, DIM, DIM);

        {
            dim3 g((MLP_DIM + 63) / 64, (M + 63) / 64);
            gemm_kernel<1, 1, 0><<<g, 256, 0, stream>>>(
                h, DIM, fc1_w + (size_t)l * DIM * MLP_DIM, fc1_b + (size_t)l * MLP_DIM,
                nullptr, hidden, MLP_DIM, M, MLP_DIM, DIM);
        }

        {
            dim3 g((DIM + 63) / 64, (M + 63) / 64);
            gemm_kernel<1, 0, 1><<<g, 256, 0, stream>>>(
                hidden, MLP_DIM, fc2_w + (size_t)l * MLP_DIM * DIM, fc2_b + (size_t)l * DIM,
                t, t, DIM, M, DIM, MLP_DIM);
        }
    }

    // ---- final LN on row 0 of each batch, then head ----
    ln_kernel<<<BATCH, 256, 0, stream>>>(t, normf_g, normf_b, pooled, N_TOK * DIM, DIM);
    {
        dim3 g((NCLS + 63) / 64, (BATCH + 63) / 64);
        gemm_kernel<1, 0, 0><<<g, 256, 0, stream>>>(pooled, DIM, head_w, head_b,
                                                    nullptr, out, NCLS, BATCH, NCLS, DIM);
    }
}

// Round 2
// 9385.365 us; speedup vs baseline: 3.5631x; 3.5631x over previous
//
#include <hip/hip_runtime.h>
#include <math.h>

#define BATCH 32
#define DEPTH 12
#define DIM 768
#define HEADS 12
#define MLP_DIM 3072
#define PATCH 16
#define GRIDSZ 14
#define NCLS 1000
#define N_TOK 197
#define HD 64
#define NPATCH 196

typedef __attribute__((ext_vector_type(8))) short short8;
typedef __attribute__((ext_vector_type(4))) float floatx4;
typedef unsigned short ushort;

// ---- manual bf16 helpers (avoid __hip_bfloat16 ctor issues in LDS arrays) ----
__device__ inline float us2f(ushort u) {
    union { unsigned int i; float f; } c; c.i = ((unsigned int)u) << 16; return c.f;
}
__device__ inline ushort f2bf(float f) {
    unsigned int x = __float_as_uint(f);
    unsigned int r = (x + 0x7fffu + ((x >> 16) & 1u)) >> 16;
    return (ushort)r;
}
__device__ inline void stv(float* p, float v) { *p = v; }
__device__ inline void stv(ushort* p, float v) { *p = f2bf(v); }

// ---- async global->LDS 16B per lane ----
#define GAS __attribute__((address_space(1)))
#define LAS __attribute__((address_space(3)))
__device__ inline void async_copy16(const void* g, void* l) {
    __builtin_amdgcn_global_load_lds((const GAS void*)g, (LAS void*)l, 16, 0, 0);
}

// ---------------------------------------------------------------------------
// im2col: x (B,3,224,224) fp32 -> patches (B*196, 768) bf16
// ---------------------------------------------------------------------------
__global__ __launch_bounds__(256) void im2col_kernel(const float* __restrict__ x,
                                                     ushort* __restrict__ patches) {
    int idx = blockIdx.x * 256 + threadIdx.x;
    const int total = BATCH * NPATCH * DIM;
    if (idx >= total) return;
    int e = idx % DIM;
    int n = (idx / DIM) % NPATCH;
    int b = idx / (DIM * NPATCH);
    int c = e / (PATCH * PATCH);
    int r = e % (PATCH * PATCH);
    int py = r / PATCH, px = r % PATCH;
    int gy = n / GRIDSZ, gx = n % GRIDSZ;
    size_t xi = (((size_t)(b * 3 + c) * 224 + gy * PATCH + py)) * 224 + gx * PATCH + px;
    patches[idx] = f2bf(x[xi]);
}

// ---------------------------------------------------------------------------
// assemble: t[b,0,:] = cls + pos[0]; t[b,n,:] = patchout[b,n-1,:] + pos[n]
// ---------------------------------------------------------------------------
__global__ __launch_bounds__(256) void assemble_kernel(const float* __restrict__ patchout,
                                                       const float* __restrict__ cls,
                                                       const float* __restrict__ pos,
                                                       float* __restrict__ t) {
    int idx = blockIdx.x * 256 + threadIdx.x;
    const int total = BATCH * N_TOK * DIM;
    if (idx >= total) return;
    int d = idx % DIM;
    int n = (idx / DIM) % N_TOK;
    int b = idx / (DIM * N_TOK);
    float v = (n == 0) ? cls[d] : patchout[((size_t)b * NPATCH + (n - 1)) * DIM + d];
    t[idx] = v + pos[n * DIM + d];
}

// ---------------------------------------------------------------------------
// LayerNorm: one block per row, 256 threads, DIM=768 = 3*256. OUT float or bf16
// ---------------------------------------------------------------------------
template <typename OUT>
__global__ __launch_bounds__(256) void ln_kernel(const float* __restrict__ x,
                                                 const float* __restrict__ g,
                                                 const float* __restrict__ bta,
                                                 OUT* __restrict__ out,
                                                 int in_stride, int out_stride) {
    int row = blockIdx.x;
    const float* xr = x + (size_t)row * in_stride;
    OUT* orow = out + (size_t)row * out_stride;
    int tid = threadIdx.x;

    float v0 = xr[tid], v1 = xr[tid + 256], v2 = xr[tid + 512];
    float s = v0 + v1 + v2;
    float s2 = v0 * v0 + v1 * v1 + v2 * v2;

    __shared__ float red[256];
    __shared__ float red2[256];
    red[tid] = s; red2[tid] = s2;
    __syncthreads();
    for (int st = 128; st > 0; st >>= 1) {
        if (tid < st) { red[tid] += red[tid + st]; red2[tid] += red2[tid + st]; }
        __syncthreads();
    }
    float mean = red[0] * (1.0f / DIM);
    float var = red2[0] * (1.0f / DIM) - mean * mean;
    float inv = rsqrtf(var + 1e-6f);

    stv(&orow[tid],       (v0 - mean) * inv * g[tid]       + bta[tid]);
    stv(&orow[tid + 256], (v1 - mean) * inv * g[tid + 256] + bta[tid + 256]);
    stv(&orow[tid + 512], (v2 - mean) * inv * g[tid + 512] + bta[tid + 512]);
}

// ---------------------------------------------------------------------------
// Weight transpose + fp32->bf16:  in K x N (row-major) -> out N x K bf16
// ---------------------------------------------------------------------------
__global__ __launch_bounds__(256) void transpose_bf16_kernel(const float* __restrict__ in,
                                                             ushort* __restrict__ out,
                                                             int K, int N) {
    __shared__ float tile[32][33];
    int n0 = blockIdx.x * 32, k0 = blockIdx.y * 32;
    int tx = threadIdx.x;  // 0..31
    int ty = threadIdx.y;  // 0..7
    for (int r = ty; r < 32; r += 8) {
        int k = k0 + r, n = n0 + tx;
        tile[r][tx] = (k < K && n < N) ? in[(size_t)k * N + n] : 0.0f;
    }
    __syncthreads();
    for (int r = ty; r < 32; r += 8) {
        int n = n0 + r, k = k0 + tx;
        if (n < N && k < K) out[(size_t)n * K + k] = f2bf(tile[tx][r]);
    }
}

// ---------------------------------------------------------------------------
// bf16 MFMA GEMM: C = epi(A[MxK] @ Wt[NxK]^T + bias)  (Wt row n holds W[:,n])
// 128x128x32 tiles, 256 thr = 4 waves (2x2 of 64x64), 16x16x32 MFMA.
// ---------------------------------------------------------------------------
template <int GELU, int RES, int WF32, int WBF16>
__global__ __launch_bounds__(256) void gemm_bf16_mfma(
    const ushort* __restrict__ A, const ushort* __restrict__ Wt,
    const float* __restrict__ bias, const float* __restrict__ res,
    float* __restrict__ Cf, ushort* __restrict__ Cb,
    int M, int N, int K) {
    __shared__ short Asm[128 * 32];
    __shared__ short Bsm[128 * 32];
    const int tid = threadIdx.x;
    const int w = tid >> 6, lane = tid & 63;
    const int wm = w >> 1, wn = w & 1;
    const int m0 = blockIdx.y * 128, n0 = blockIdx.x * 128;

    floatx4 acc[4][4] = {};

    // staging: wave w covers tile rows [w*32, w*32+32), 2 instrs (16 rows each);
    // lane -> row w*32+q*16+(lane>>2), 16B col chunk (lane&3)*8 elems
    const int srow = lane >> 2;
    const int scol = (lane & 3) * 8;
    int ar0 = min(m0 + w * 32 + srow, M - 1);
    int ar1 = min(m0 + w * 32 + 16 + srow, M - 1);
    int br0 = min(n0 + w * 32 + srow, N - 1);
    int br1 = min(n0 + w * 32 + 16 + srow, N - 1);
    const ushort* a0 = A + (size_t)ar0 * K + scol;
    const ushort* a1 = A + (size_t)ar1 * K + scol;
    const ushort* b0 = Wt + (size_t)br0 * K + scol;
    const ushort* b1 = Wt + (size_t)br1 * K + scol;
    short* lA0 = Asm + (w * 32) * 32;
    short* lA1 = Asm + (w * 32 + 16) * 32;
    short* lB0 = Bsm + (w * 32) * 32;
    short* lB1 = Bsm + (w * 32 + 16) * 32;

    const int fr = lane & 15, quad = lane >> 4;
    const int aoff = (wm * 64 + fr) * 32 + quad * 8;  // + mt*16*32
    const int boff = (wn * 64 + fr) * 32 + quad * 8;  // + nt*16*32

    for (int k0 = 0; k0 < K; k0 += 32) {
        async_copy16(a0 + k0, lA0);
        async_copy16(a1 + k0, lA1);
        async_copy16(b0 + k0, lB0);
        async_copy16(b1 + k0, lB1);
        __syncthreads();
        short8 af[4], bf[4];
#pragma unroll
        for (int mt = 0; mt < 4; mt++) af[mt] = *(const short8*)&Asm[aoff + mt * 512];
#pragma unroll
        for (int nt = 0; nt < 4; nt++) bf[nt] = *(const short8*)&Bsm[boff + nt * 512];
#pragma unroll
        for (int mt = 0; mt < 4; mt++)
#pragma unroll
            for (int nt = 0; nt < 4; nt++)
                acc[mt][nt] = __builtin_amdgcn_mfma_f32_16x16x32_bf16(af[mt], bf[nt], acc[mt][nt], 0, 0, 0);
        __syncthreads();
    }

    // epilogue: D row = wm*64+mt*16+quad*4+r, col = wn*64+nt*16+fr
#pragma unroll
    for (int nt = 0; nt < 4; nt++) {
        int col = n0 + wn * 64 + nt * 16 + fr;
        if (col >= N) continue;
        float bv = bias[col];
#pragma unroll
        for (int mt = 0; mt < 4; mt++) {
            int rbase = m0 + wm * 64 + mt * 16 + quad * 4;
#pragma unroll
            for (int r = 0; r < 4; r++) {
                int row = rbase + r;
                if (row >= M) continue;
                float v = acc[mt][nt][r] + bv;
                if (GELU) v = 0.5f * v * (1.0f + erff(v * 0.70710678118654752f));
                if (RES) v += res[(size_t)row * N + col];
                if (WF32) Cf[(size_t)row * N + col] = v;
                if (WBF16) Cb[(size_t)row * N + col] = f2bf(v);
            }
        }
    }
}

// ---------------------------------------------------------------------------
// Attention: one block per (h, b). K/V staged in LDS (bf16), wave per query.
// qkv bf16 layout: [(b*197+n)*3 + c][768], col = h*64 + d.
// ---------------------------------------------------------------------------
__global__ __launch_bounds__(256) void attn_kernel(const ushort* __restrict__ qkvb,
                                                   const float* __restrict__ mask,
                                                   ushort* __restrict__ o) {
    const int h = blockIdx.x, b = blockIdx.y;
    __shared__ ushort Kb[N_TOK][HD];
    __shared__ ushort Vb[N_TOK][HD];
    __shared__ float ps[4][200];
    const int tid = threadIdx.x;

    for (int idx = tid; idx < N_TOK * 16; idx += 256) {
        int j = idx >> 4, c = (idx & 15) * 4;
        size_t base = (size_t)(b * N_TOK + j) * 3;
        *(uint2*)&Kb[j][c] = *(const uint2*)(qkvb + (base + 1) * DIM + h * HD + c);
        *(uint2*)&Vb[j][c] = *(const uint2*)(qkvb + (base + 2) * DIM + h * HD + c);
    }
    __syncthreads();

    const int w = tid >> 6, l = tid & 63;
    const int j0 = l, j1 = l + 64, j2 = l + 128, j3 = l + 192;
    const int j3c = min(j3, N_TOK - 1);

    for (int i = w; i < N_TOK; i += 4) {
        float qreg = us2f(qkvb[((size_t)(b * N_TOK + i) * 3) * DIM + h * HD + l]);
        float s0 = 0, s1 = 0, s2 = 0, s3 = 0;
#pragma unroll 8
        for (int t = 0; t < 64; t++) {
            int d = (t + l) & 63;  // lane-rotation: conflict-free LDS banks
            float qd = __shfl(qreg, d);
            s0 += qd * us2f(Kb[j0][d]);
            s1 += qd * us2f(Kb[j1][d]);
            s2 += qd * us2f(Kb[j2][d]);
            s3 += qd * us2f(Kb[j3c][d]);
        }
        const float scale = 0.125f;
        const float* mrow = mask + i * N_TOK;
        s0 = s0 * scale * mrow[j0];
        s1 = s1 * scale * mrow[j1];
        s2 = s2 * scale * mrow[j2];
        s3 = (j3 < N_TOK) ? s3 * scale * mrow[j3] : -INFINITY;

        float m = fmaxf(fmaxf(s0, s1), fmaxf(s2, s3));
        for (int off = 32; off; off >>= 1) m = fmaxf(m, __shfl_xor(m, off));
        float e0 = __expf(s0 - m), e1 = __expf(s1 - m), e2 = __expf(s2 - m);
        float e3 = (j3 < N_TOK) ? __expf(s3 - m) : 0.0f;
        float sum = e0 + e1 + e2 + e3;
        for (int off = 32; off; off >>= 1) sum += __shfl_xor(sum, off);
        float inv = 1.0f / sum;

        ps[w][j0] = e0; ps[w][j1] = e1; ps[w][j2] = e2;
        if (j3 < N_TOK) ps[w][j3] = e3;
        __threadfence_block();

        float oacc = 0.0f;
        for (int j = 0; j < N_TOK; j++)
            oacc += ps[w][j] * us2f(Vb[j][l]);
        o[((size_t)(b * N_TOK + i)) * DIM + h * HD + l] = f2bf(oacc * inv);
        __threadfence_block();
    }
}

// ---------------------------------------------------------------------------
extern "C" void kernel_launch(void* const* d_in, const int* in_sizes, int n_in,
                              void* d_out, int out_size, void* d_ws, size_t ws_size,
                              hipStream_t stream) {
    const float* x       = (const float*)d_in[0];
    const float* cp_mask = (const float*)d_in[1];
    const float* patch_w = (const float*)d_in[2];
    const float* patch_b = (const float*)d_in[3];
    const float* cls_tok = (const float*)d_in[4];
    const float* pos_emb = (const float*)d_in[5];
    const float* ln1_g   = (const float*)d_in[6];
    const float* ln1_b   = (const float*)d_in[7];
    const float* qkv_w   = (const float*)d_in[8];
    const float* qkv_b   = (const float*)d_in[9];
    const float* proj_w  = (const float*)d_in[10];
    const float* proj_b  = (const float*)d_in[11];
    const float* ln2_g   = (const float*)d_in[12];
    const float* ln2_b   = (const float*)d_in[13];
    const float* fc1_w   = (const float*)d_in[14];
    const float* fc1_b   = (const float*)d_in[15];
    const float* fc2_w   = (const float*)d_in[16];
    const float* fc2_b   = (const float*)d_in[17];
    const float* normf_g = (const float*)d_in[18];
    const float* normf_b = (const float*)d_in[19];
    const float* head_w  = (const float*)d_in[20];
    const float* head_b  = (const float*)d_in[21];
    float* out = (float*)d_out;

    const int M = BATCH * N_TOK;  // 6304
    char* p = (char*)d_ws;
    auto alloc = [&](size_t bytes) { char* r = p; p += (bytes + 255) & ~(size_t)255; return r; };
    float*  t         = (float*)alloc((size_t)M * DIM * 4);
    float*  patchout  = (float*)alloc((size_t)BATCH * NPATCH * DIM * 4);
    ushort* h_bf      = (ushort*)alloc((size_t)M * DIM * 2);      // also patches_bf pre-loop
    ushort* qkv_bf    = (ushort*)alloc((size_t)M * 3 * DIM * 2);
    ushort* o_bf      = (ushort*)alloc((size_t)M * DIM * 2);
    ushort* hidden_bf = (ushort*)alloc((size_t)M * MLP_DIM * 2);
    ushort* pooled_bf = (ushort*)alloc((size_t)BATCH * DIM * 2);
    ushort* wq_t      = (ushort*)alloc((size_t)3 * DIM * DIM * 2);
    ushort* wp_t      = (ushort*)alloc((size_t)DIM * DIM * 2);
    ushort* w1_t      = (ushort*)alloc((size_t)MLP_DIM * DIM * 2);
    ushort* w2_t      = (ushort*)alloc((size_t)DIM * MLP_DIM * 2);
    ushort* wpt       = (ushort*)alloc((size_t)DIM * DIM * 2);
    ushort* wht       = (ushort*)alloc((size_t)NCLS * DIM * 2);

    const dim3 tb(32, 8);

    // ---- patch embedding ----
    transpose_bf16_kernel<<<dim3(24, 24), tb, 0, stream>>>(patch_w, wpt, DIM, DIM);
    transpose_bf16_kernel<<<dim3(32, 24), tb, 0, stream>>>(head_w, wht, DIM, NCLS);
    {
        int total = BATCH * NPATCH * DIM;
        im2col_kernel<<<(total + 255) / 256, 256, 0, stream>>>(x, h_bf);
        gemm_bf16_mfma<0, 0, 1, 0><<<dim3(6, 49), 256, 0, stream>>>(
            h_bf, wpt, patch_b, nullptr, patchout, nullptr, BATCH * NPATCH, DIM, DIM);
        int total2 = M * DIM;
        assemble_kernel<<<(total2 + 255) / 256, 256, 0, stream>>>(patchout, cls_tok, pos_emb, t);
    }

    // ---- transformer layers ----
    for (int l = 0; l < DEPTH; l++) {
        transpose_bf16_kernel<<<dim3(72, 24), tb, 0, stream>>>(qkv_w + (size_t)l * DIM * 3 * DIM, wq_t, DIM, 3 * DIM);
        transpose_bf16_kernel<<<dim3(24, 24), tb, 0, stream>>>(proj_w + (size_t)l * DIM * DIM, wp_t, DIM, DIM);
        transpose_bf16_kernel<<<dim3(96, 24), tb, 0, stream>>>(fc1_w + (size_t)l * DIM * MLP_DIM, w1_t, DIM, MLP_DIM);
        transpose_bf16_kernel<<<dim3(24, 96), tb, 0, stream>>>(fc2_w + (size_t)l * MLP_DIM * DIM, w2_t, MLP_DIM, DIM);

        ln_kernel<ushort><<<M, 256, 0, stream>>>(t, ln1_g + l * DIM, ln1_b + l * DIM, h_bf, DIM, DIM);

        gemm_bf16_mfma<0, 0, 0, 1><<<dim3(18, 50), 256, 0, stream>>>(
            h_bf, wq_t, qkv_b + (size_t)l * 3 * DIM, nullptr, nullptr, qkv_bf, M, 3 * DIM, DIM);

        attn_kernel<<<dim3(HEADS, BATCH), 256, 0, stream>>>(qkv_bf, cp_mask, o_bf);

        gemm_bf16_mfma<0, 1, 1, 0><<<dim3(6, 50), 256, 0, stream>>>(
            o_bf, wp_t, proj_b + (size_t)l * DIM, t, t, nullptr, M, DIM, DIM);

        ln_kernel<ushort><<<M, 256, 0, stream>>>(t, ln2_g + l * DIM, ln2_b + l * DIM, h_bf, DIM, DIM);

        gemm_bf16_mfma<1, 0, 0, 1><<<dim3(24, 50), 256, 0, stream>>>(
            h_bf, w1_t, fc1_b + (size_t)l * MLP_DIM, nullptr, nullptr, hidden_bf, M, MLP_DIM, DIM);

        gemm_bf16_mfma<0, 1, 1, 0><<<dim3(6, 50), 256, 0, stream>>>(
            hidden_bf, w2_t, fc2_b + (size_t)l * DIM, t, t, nullptr, M, DIM, MLP_DIM);
    }

    // ---- final LN (CLS rows) + head ----
    ln_kernel<ushort><<<BATCH, 256, 0, stream>>>(t, normf_g, normf_b, pooled_bf, N_TOK * DIM, DIM);
    gemm_bf16_mfma<0, 0, 1, 0><<<dim3(8, 1), 256, 0, stream>>>(
        pooled_bf, wht, head_b, nullptr, out, nullptr, BATCH, NCLS, DIM);
}

// Round 3
// 4369.600 us; speedup vs baseline: 7.6531x; 2.1479x over previous
//
#include <hip/hip_runtime.h>
#include <math.h>

#define BATCH 32
#define DEPTH 12
#define DIM 768
#define HEADS 12
#define MLP_DIM 3072
#define PATCH 16
#define GRIDSZ 14
#define NCLS 1000
#define N_TOK 197
#define HD 64
#define NPATCH 196

typedef __attribute__((ext_vector_type(8))) short short8;
typedef __attribute__((ext_vector_type(4))) float floatx4;
typedef unsigned short ushort;

__device__ inline float us2f(ushort u) {
    union { unsigned int i; float f; } c; c.i = ((unsigned int)u) << 16; return c.f;
}
__device__ inline ushort f2bf(float f) {
    unsigned int x = __float_as_uint(f);
    unsigned int r = (x + 0x7fffu + ((x >> 16) & 1u)) >> 16;
    return (ushort)r;
}
__device__ inline void stv(float* p, float v) { *p = v; }
__device__ inline void stv(ushort* p, float v) { *p = f2bf(v); }

#define GAS __attribute__((address_space(1)))
#define LAS __attribute__((address_space(3)))
__device__ inline void async_copy16(const void* g, void* l) {
    __builtin_amdgcn_global_load_lds((const GAS void*)g, (LAS void*)l, 16, 0, 0);
}

// ---------------------------------------------------------------------------
__global__ __launch_bounds__(256) void im2col_kernel(const float* __restrict__ x,
                                                     ushort* __restrict__ patches) {
    int idx = blockIdx.x * 256 + threadIdx.x;
    const int total = BATCH * NPATCH * DIM;
    if (idx >= total) return;
    int e = idx % DIM;
    int n = (idx / DIM) % NPATCH;
    int b = idx / (DIM * NPATCH);
    int c = e / (PATCH * PATCH);
    int r = e % (PATCH * PATCH);
    int py = r / PATCH, px = r % PATCH;
    int gy = n / GRIDSZ, gx = n % GRIDSZ;
    size_t xi = (((size_t)(b * 3 + c) * 224 + gy * PATCH + py)) * 224 + gx * PATCH + px;
    patches[idx] = f2bf(x[xi]);
}

// ---------------------------------------------------------------------------
__global__ __launch_bounds__(256) void assemble_kernel(const float* __restrict__ patchout,
                                                       const float* __restrict__ cls,
                                                       const float* __restrict__ pos,
                                                       float* __restrict__ t) {
    int idx = blockIdx.x * 256 + threadIdx.x;
    const int total = BATCH * N_TOK * DIM;
    if (idx >= total) return;
    int d = idx % DIM;
    int n = (idx / DIM) % N_TOK;
    int b = idx / (DIM * N_TOK);
    float v = (n == 0) ? cls[d] : patchout[((size_t)b * NPATCH + (n - 1)) * DIM + d];
    t[idx] = v + pos[n * DIM + d];
}

// ---------------------------------------------------------------------------
template <typename OUT>
__global__ __launch_bounds__(256) void ln_kernel(const float* __restrict__ x,
                                                 const float* __restrict__ g,
                                                 const float* __restrict__ bta,
                                                 OUT* __restrict__ out,
                                                 int in_stride, int out_stride) {
    int row = blockIdx.x;
    const float* xr = x + (size_t)row * in_stride;
    OUT* orow = out + (size_t)row * out_stride;
    int tid = threadIdx.x;

    float v0 = xr[tid], v1 = xr[tid + 256], v2 = xr[tid + 512];
    float s = v0 + v1 + v2;
    float s2 = v0 * v0 + v1 * v1 + v2 * v2;

    __shared__ float red[256];
    __shared__ float red2[256];
    red[tid] = s; red2[tid] = s2;
    __syncthreads();
    for (int st = 128; st > 0; st >>= 1) {
        if (tid < st) { red[tid] += red[tid + st]; red2[tid] += red2[tid + st]; }
        __syncthreads();
    }
    float mean = red[0] * (1.0f / DIM);
    float var = red2[0] * (1.0f / DIM) - mean * mean;
    float inv = rsqrtf(var + 1e-6f);

    stv(&orow[tid],       (v0 - mean) * inv * g[tid]       + bta[tid]);
    stv(&orow[tid + 256], (v1 - mean) * inv * g[tid + 256] + bta[tid + 256]);
    stv(&orow[tid + 512], (v2 - mean) * inv * g[tid + 512] + bta[tid + 512]);
}

// ---------------------------------------------------------------------------
__global__ __launch_bounds__(256) void transpose_bf16_kernel(const float* __restrict__ in,
                                                             ushort* __restrict__ out,
                                                             int K, int N) {
    __shared__ float tile[32][33];
    int n0 = blockIdx.x * 32, k0 = blockIdx.y * 32;
    int tx = threadIdx.x;
    int ty = threadIdx.y;
    for (int r = ty; r < 32; r += 8) {
        int k = k0 + r, n = n0 + tx;
        tile[r][tx] = (k < K && n < N) ? in[(size_t)k * N + n] : 0.0f;
    }
    __syncthreads();
    for (int r = ty; r < 32; r += 8) {
        int n = n0 + r, k = k0 + tx;
        if (n < N && k < K) out[(size_t)n * K + k] = f2bf(tile[tx][r]);
    }
}

// ---------------------------------------------------------------------------
// bf16 MFMA GEMM (m97-style): 128x128x32 tiles, 4 waves, 16x16x32 MFMA.
// ---------------------------------------------------------------------------
template <int GELU, int RES, int WF32, int WBF16>
__global__ __launch_bounds__(256) void gemm_bf16_mfma(
    const ushort* __restrict__ A, const ushort* __restrict__ Wt,
    const float* __restrict__ bias, const float* __restrict__ res,
    float* __restrict__ Cf, ushort* __restrict__ Cb,
    int M, int N, int K) {
    __shared__ short Asm[128 * 32];
    __shared__ short Bsm[128 * 32];
    const int tid = threadIdx.x;
    const int w = tid >> 6, lane = tid & 63;
    const int wm = w >> 1, wn = w & 1;
    const int m0 = blockIdx.y * 128, n0 = blockIdx.x * 128;

    floatx4 acc[4][4] = {};

    const int srow = lane >> 2;
    const int scol = (lane & 3) * 8;
    int ar0 = min(m0 + w * 32 + srow, M - 1);
    int ar1 = min(m0 + w * 32 + 16 + srow, M - 1);
    int br0 = min(n0 + w * 32 + srow, N - 1);
    int br1 = min(n0 + w * 32 + 16 + srow, N - 1);
    const ushort* a0 = A + (size_t)ar0 * K + scol;
    const ushort* a1 = A + (size_t)ar1 * K + scol;
    const ushort* b0 = Wt + (size_t)br0 * K + scol;
    const ushort* b1 = Wt + (size_t)br1 * K + scol;
    short* lA0 = Asm + (w * 32) * 32;
    short* lA1 = Asm + (w * 32 + 16) * 32;
    short* lB0 = Bsm + (w * 32) * 32;
    short* lB1 = Bsm + (w * 32 + 16) * 32;

    const int fr = lane & 15, quad = lane >> 4;
    const int aoff = (wm * 64 + fr) * 32 + quad * 8;
    const int boff = (wn * 64 + fr) * 32 + quad * 8;

    for (int k0 = 0; k0 < K; k0 += 32) {
        async_copy16(a0 + k0, lA0);
        async_copy16(a1 + k0, lA1);
        async_copy16(b0 + k0, lB0);
        async_copy16(b1 + k0, lB1);
        __syncthreads();
        short8 af[4], bf[4];
#pragma unroll
        for (int mt = 0; mt < 4; mt++) af[mt] = *(const short8*)&Asm[aoff + mt * 512];
#pragma unroll
        for (int nt = 0; nt < 4; nt++) bf[nt] = *(const short8*)&Bsm[boff + nt * 512];
#pragma unroll
        for (int mt = 0; mt < 4; mt++)
#pragma unroll
            for (int nt = 0; nt < 4; nt++)
                acc[mt][nt] = __builtin_amdgcn_mfma_f32_16x16x32_bf16(af[mt], bf[nt], acc[mt][nt], 0, 0, 0);
        __syncthreads();
    }

#pragma unroll
    for (int nt = 0; nt < 4; nt++) {
        int col = n0 + wn * 64 + nt * 16 + fr;
        if (col >= N) continue;
        float bv = bias[col];
#pragma unroll
        for (int mt = 0; mt < 4; mt++) {
            int rbase = m0 + wm * 64 + mt * 16 + quad * 4;
#pragma unroll
            for (int r = 0; r < 4; r++) {
                int row = rbase + r;
                if (row >= M) continue;
                float v = acc[mt][nt][r] + bv;
                if (GELU) v = 0.5f * v * (1.0f + erff(v * 0.70710678118654752f));
                if (RES) v += res[(size_t)row * N + col];
                if (WF32) Cf[(size_t)row * N + col] = v;
                if (WBF16) Cb[(size_t)row * N + col] = f2bf(v);
            }
        }
    }
}

// ---------------------------------------------------------------------------
// MFMA attention. Block = (h, b), 4 waves. Wave handles query tiles
// qt = w, w+4, ... (13 tiles of 16 over 197 queries).
//   QK^T: A-frag = Q from global (16B/lane), B-frag = K from global (16B/lane,
//         L2-resident). S kept in C-layout regs (13 x float4).
//   softmax: scale*mask, quad shfl_xor row-reduce, exp, row sums.
//   P: written to per-wave LDS region in A-frag order; V pre-staged in LDS in
//      B-frag-gathered order -> all frag reads are lane-contiguous b128.
// ---------------------------------------------------------------------------
__global__ __launch_bounds__(256, 2) void attn_kernel(const ushort* __restrict__ qkvb,
                                                      const float* __restrict__ mask,
                                                      ushort* __restrict__ o) {
    const int h = blockIdx.x, b = blockIdx.y;
    const int tid = threadIdx.x;
    // V in B-frag gather order: [kt(7)][dt(4)][lane(64)][8], keys padded to 224
    __shared__ ushort Vfrag[7 * 4 * 64 * 8];   // 28672 B
    // P per wave in A-frag order: [w(4)][kt(7)][lane(64)][8]
    __shared__ ushort Pfrag[4 * 7 * 64 * 8];   // 28672 B

    // zero both (covers key padding 197..223 and jj-pad)
    {
        uint4 z = {0, 0, 0, 0};
        uint4* v4 = (uint4*)Vfrag;
        uint4* p4 = (uint4*)Pfrag;
        for (int i = tid; i < 1792; i += 256) { v4[i] = z; p4[i] = z; }
    }
    __syncthreads();

    // stage V: coalesced uint reads, scatter b16 to frag layout
    for (int pass = 0; pass < 25; pass++) {
        int j = pass * 8 + (tid >> 5);
        if (j <= 196) {
            int d0 = (tid & 31) * 2;
            unsigned int val = *(const unsigned int*)(qkvb + ((size_t)(b * N_TOK + j) * 3 + 2) * DIM + h * HD + d0);
            int kt = j >> 5, dt = d0 >> 4;
            int lane = ((j & 31) >> 3) * 16 + (d0 & 15);
            int jj = j & 7;
            int base = (kt * 4 + dt) * 512 + lane * 8 + jj;
            Vfrag[base] = (ushort)(val & 0xffffu);
            Vfrag[base + 8] = (ushort)(val >> 16);
        }
    }
    __syncthreads();

    const int w = tid >> 6, l = tid & 63;
    const int q = l >> 4, fr = l & 15;
    ushort* Pw = Pfrag + w * 3584;
    const float scale = 0.125f;

    for (int qt = w; qt < 13; qt += 4) {
        // ---- Q A-frags (2 k-chunks of 32 over HD=64) ----
        int qrow = min(qt * 16 + fr, 196);
        const ushort* qptr = qkvb + ((size_t)(b * N_TOK + qrow) * 3 + 0) * DIM + h * HD + q * 8;
        short8 aq0 = *(const short8*)qptr;
        short8 aq1 = *(const short8*)(qptr + 32);

        // ---- S = Q @ K^T over 13 key tiles ----
        floatx4 sacc[13];
#pragma unroll
        for (int nt = 0; nt < 13; nt++) {
            int krow = min(nt * 16 + fr, 196);
            const ushort* kptr = qkvb + ((size_t)(b * N_TOK + krow) * 3 + 1) * DIM + h * HD + q * 8;
            short8 kb0 = *(const short8*)kptr;
            short8 kb1 = *(const short8*)(kptr + 32);
            floatx4 acc = {};
            acc = __builtin_amdgcn_mfma_f32_16x16x32_bf16(aq0, kb0, acc, 0, 0, 0);
            acc = __builtin_amdgcn_mfma_f32_16x16x32_bf16(aq1, kb1, acc, 0, 0, 0);
            sacc[nt] = acc;
        }

        // ---- scale * mask, row max ----
        float mx[4] = {-1e30f, -1e30f, -1e30f, -1e30f};
#pragma unroll
        for (int nt = 0; nt < 13; nt++) {
            int jcol = nt * 16 + fr;
#pragma unroll
            for (int r = 0; r < 4; r++) {
                int irow = min(qt * 16 + q * 4 + r, 196);
                float s;
                if (jcol <= 196) s = sacc[nt][r] * scale * mask[irow * N_TOK + jcol];
                else s = -1e30f;
                sacc[nt][r] = s;
                mx[r] = fmaxf(mx[r], s);
            }
        }
#pragma unroll
        for (int r = 0; r < 4; r++) {
            mx[r] = fmaxf(mx[r], __shfl_xor(mx[r], 1));
            mx[r] = fmaxf(mx[r], __shfl_xor(mx[r], 2));
            mx[r] = fmaxf(mx[r], __shfl_xor(mx[r], 4));
            mx[r] = fmaxf(mx[r], __shfl_xor(mx[r], 8));
        }

        // ---- exp, row sums, write P to LDS in A-frag order ----
        float sum[4] = {0, 0, 0, 0};
#pragma unroll
        for (int nt = 0; nt < 13; nt++) {
            int kt = nt >> 1;
            int lpbase = ((nt & 1) * 2 + ((l & 8) >> 3)) * 16;
#pragma unroll
            for (int r = 0; r < 4; r++) {
                float e = __expf(sacc[nt][r] - mx[r]);
                sum[r] += e;
                int lp = (q * 4 + r) + lpbase;
                Pw[kt * 512 + lp * 8 + (l & 7)] = f2bf(e);
            }
        }
#pragma unroll
        for (int r = 0; r < 4; r++) {
            sum[r] += __shfl_xor(sum[r], 1);
            sum[r] += __shfl_xor(sum[r], 2);
            sum[r] += __shfl_xor(sum[r], 4);
            sum[r] += __shfl_xor(sum[r], 8);
        }

        // ---- O = P @ V ----
        floatx4 oacc[4] = {};
#pragma unroll
        for (int kt = 0; kt < 7; kt++) {
            short8 pa = *(const short8*)&Pw[kt * 512 + l * 8];
#pragma unroll
            for (int dt = 0; dt < 4; dt++) {
                short8 vb = *(const short8*)&Vfrag[(kt * 4 + dt) * 512 + l * 8];
                oacc[dt] = __builtin_amdgcn_mfma_f32_16x16x32_bf16(pa, vb, oacc[dt], 0, 0, 0);
            }
        }

        // ---- write O (bf16) ----
        float inv[4];
#pragma unroll
        for (int r = 0; r < 4; r++) inv[r] = 1.0f / sum[r];
#pragma unroll
        for (int dt = 0; dt < 4; dt++) {
#pragma unroll
            for (int r = 0; r < 4; r++) {
                int irow = qt * 16 + q * 4 + r;
                if (irow <= 196)
                    o[((size_t)(b * N_TOK + irow)) * DIM + h * HD + dt * 16 + fr] = f2bf(oacc[dt][r] * inv[r]);
            }
        }
    }
}

// ---------------------------------------------------------------------------
extern "C" void kernel_launch(void* const* d_in, const int* in_sizes, int n_in,
                              void* d_out, int out_size, void* d_ws, size_t ws_size,
                              hipStream_t stream) {
    const float* x       = (const float*)d_in[0];
    const float* cp_mask = (const float*)d_in[1];
    const float* patch_w = (const float*)d_in[2];
    const float* patch_b = (const float*)d_in[3];
    const float* cls_tok = (const float*)d_in[4];
    const float* pos_emb = (const float*)d_in[5];
    const float* ln1_g   = (const float*)d_in[6];
    const float* ln1_b   = (const float*)d_in[7];
    const float* qkv_w   = (const float*)d_in[8];
    const float* qkv_b   = (const float*)d_in[9];
    const float* proj_w  = (const float*)d_in[10];
    const float* proj_b  = (const float*)d_in[11];
    const float* ln2_g   = (const float*)d_in[12];
    const float* ln2_b   = (const float*)d_in[13];
    const float* fc1_w   = (const float*)d_in[14];
    const float* fc1_b   = (const float*)d_in[15];
    const float* fc2_w   = (const float*)d_in[16];
    const float* fc2_b   = (const float*)d_in[17];
    const float* normf_g = (const float*)d_in[18];
    const float* normf_b = (const float*)d_in[19];
    const float* head_w  = (const float*)d_in[20];
    const float* head_b  = (const float*)d_in[21];
    float* out = (float*)d_out;

    const int M = BATCH * N_TOK;  // 6304
    char* p = (char*)d_ws;
    auto alloc = [&](size_t bytes) { char* r = p; p += (bytes + 255) & ~(size_t)255; return r; };
    float*  t         = (float*)alloc((size_t)M * DIM * 4);
    float*  patchout  = (float*)alloc((size_t)BATCH * NPATCH * DIM * 4);
    ushort* h_bf      = (ushort*)alloc((size_t)M * DIM * 2);
    ushort* qkv_bf    = (ushort*)alloc((size_t)M * 3 * DIM * 2);
    ushort* o_bf      = (ushort*)alloc((size_t)M * DIM * 2);
    ushort* hidden_bf = (ushort*)alloc((size_t)M * MLP_DIM * 2);
    ushort* pooled_bf = (ushort*)alloc((size_t)BATCH * DIM * 2);
    ushort* wq_t      = (ushort*)alloc((size_t)3 * DIM * DIM * 2);
    ushort* wp_t      = (ushort*)alloc((size_t)DIM * DIM * 2);
    ushort* w1_t      = (ushort*)alloc((size_t)MLP_DIM * DIM * 2);
    ushort* w2_t      = (ushort*)alloc((size_t)DIM * MLP_DIM * 2);
    ushort* wpt       = (ushort*)alloc((size_t)DIM * DIM * 2);
    ushort* wht       = (ushort*)alloc((size_t)NCLS * DIM * 2);

    const dim3 tb(32, 8);

    transpose_bf16_kernel<<<dim3(24, 24), tb, 0, stream>>>(patch_w, wpt, DIM, DIM);
    transpose_bf16_kernel<<<dim3(32, 24), tb, 0, stream>>>(head_w, wht, DIM, NCLS);
    {
        int total = BATCH * NPATCH * DIM;
        im2col_kernel<<<(total + 255) / 256, 256, 0, stream>>>(x, h_bf);
        gemm_bf16_mfma<0, 0, 1, 0><<<dim3(6, 49), 256, 0, stream>>>(
            h_bf, wpt, patch_b, nullptr, patchout, nullptr, BATCH * NPATCH, DIM, DIM);
        int total2 = M * DIM;
        assemble_kernel<<<(total2 + 255) / 256, 256, 0, stream>>>(patchout, cls_tok, pos_emb, t);
    }

    for (int l = 0; l < DEPTH; l++) {
        transpose_bf16_kernel<<<dim3(72, 24), tb, 0, stream>>>(qkv_w + (size_t)l * DIM * 3 * DIM, wq_t, DIM, 3 * DIM);
        transpose_bf16_kernel<<<dim3(24, 24), tb, 0, stream>>>(proj_w + (size_t)l * DIM * DIM, wp_t, DIM, DIM);
        transpose_bf16_kernel<<<dim3(96, 24), tb, 0, stream>>>(fc1_w + (size_t)l * DIM * MLP_DIM, w1_t, DIM, MLP_DIM);
        transpose_bf16_kernel<<<dim3(24, 96), tb, 0, stream>>>(fc2_w + (size_t)l * MLP_DIM * DIM, w2_t, MLP_DIM, DIM);

        ln_kernel<ushort><<<M, 256, 0, stream>>>(t, ln1_g + l * DIM, ln1_b + l * DIM, h_bf, DIM, DIM);

        gemm_bf16_mfma<0, 0, 0, 1><<<dim3(18, 50), 256, 0, stream>>>(
            h_bf, wq_t, qkv_b + (size_t)l * 3 * DIM, nullptr, nullptr, qkv_bf, M, 3 * DIM, DIM);

        attn_kernel<<<dim3(HEADS, BATCH), 256, 0, stream>>>(qkv_bf, cp_mask, o_bf);

        gemm_bf16_mfma<0, 1, 1, 0><<<dim3(6, 50), 256, 0, stream>>>(
            o_bf, wp_t, proj_b + (size_t)l * DIM, t, t, nullptr, M, DIM, DIM);

        ln_kernel<ushort><<<M, 256, 0, stream>>>(t, ln2_g + l * DIM, ln2_b + l * DIM, h_bf, DIM, DIM);

        gemm_bf16_mfma<1, 0, 0, 1><<<dim3(24, 50), 256, 0, stream>>>(
            h_bf, w1_t, fc1_b + (size_t)l * MLP_DIM, nullptr, nullptr, hidden_bf, M, MLP_DIM, DIM);

        gemm_bf16_mfma<0, 1, 1, 0><<<dim3(6, 50), 256, 0, stream>>>(
            hidden_bf, w2_t, fc2_b + (size_t)l * DIM, t, t, nullptr, M, DIM, MLP_DIM);
    }

    ln_kernel<ushort><<<BATCH, 256, 0, stream>>>(t, normf_g, normf_b, pooled_bf, N_TOK * DIM, DIM);
    gemm_bf16_mfma<0, 0, 1, 0><<<dim3(8, 1), 256, 0, stream>>>(
        pooled_bf, wht, head_b, nullptr, out, nullptr, BATCH, NCLS, DIM);
}

// Round 4
// 3394.999 us; speedup vs baseline: 9.8501x; 1.2871x over previous
//
#include <hip/hip_runtime.h>
#include <math.h>

#define BATCH 32
#define DEPTH 12
#define DIM 768
#define HEADS 12
#define MLP_DIM 3072
#define PATCH 16
#define GRIDSZ 14
#define NCLS 1000
#define N_TOK 197
#define HD 64
#define NPATCH 196

typedef __attribute__((ext_vector_type(8))) short short8;
typedef __attribute__((ext_vector_type(4))) float floatx4;
typedef unsigned short ushort;

__device__ inline float us2f(ushort u) {
    union { unsigned int i; float f; } c; c.i = ((unsigned int)u) << 16; return c.f;
}
__device__ inline ushort f2bf(float f) {
    unsigned int x = __float_as_uint(f);
    unsigned int r = (x + 0x7fffu + ((x >> 16) & 1u)) >> 16;
    return (ushort)r;
}

#define GAS __attribute__((address_space(1)))
#define LAS __attribute__((address_space(3)))
__device__ inline void async_copy16(const void* g, void* l) {
    __builtin_amdgcn_global_load_lds((const GAS void*)g, (LAS void*)l, 16, 0, 0);
}

// ---------------------------------------------------------------------------
__global__ __launch_bounds__(256) void im2col_kernel(const float* __restrict__ x,
                                                     ushort* __restrict__ patches) {
    int idx = blockIdx.x * 256 + threadIdx.x;
    const int total = BATCH * NPATCH * DIM;
    if (idx >= total) return;
    int e = idx % DIM;
    int n = (idx / DIM) % NPATCH;
    int b = idx / (DIM * NPATCH);
    int c = e / (PATCH * PATCH);
    int r = e % (PATCH * PATCH);
    int py = r / PATCH, px = r % PATCH;
    int gy = n / GRIDSZ, gx = n % GRIDSZ;
    size_t xi = (((size_t)(b * 3 + c) * 224 + gy * PATCH + py)) * 224 + gx * PATCH + px;
    patches[idx] = f2bf(x[xi]);
}

// ---------------------------------------------------------------------------
__global__ __launch_bounds__(256) void assemble_kernel(const float* __restrict__ patchout,
                                                       const float* __restrict__ cls,
                                                       const float* __restrict__ pos,
                                                       float* __restrict__ t) {
    int idx = blockIdx.x * 256 + threadIdx.x;
    const int total = BATCH * N_TOK * DIM;
    if (idx >= total) return;
    int d = idx % DIM;
    int n = (idx / DIM) % N_TOK;
    int b = idx / (DIM * N_TOK);
    float v = (n == 0) ? cls[d] : patchout[((size_t)b * NPATCH + (n - 1)) * DIM + d];
    t[idx] = v + pos[n * DIM + d];
}

// ---------------------------------------------------------------------------
// LayerNorm, wave-per-row: block = 4 waves = 4 rows. 768 = 64 lanes * 12.
// ---------------------------------------------------------------------------
__global__ __launch_bounds__(256) void lnw_kernel(const float* __restrict__ x,
                                                  const float* __restrict__ g,
                                                  const float* __restrict__ bta,
                                                  ushort* __restrict__ out,
                                                  int rows, int in_stride, int out_stride) {
    int w = threadIdx.x >> 6, l = threadIdx.x & 63;
    int row = blockIdx.x * 4 + w;
    if (row >= rows) return;
    const float* xr = x + (size_t)row * in_stride;
    float4 v[3];
    float s = 0.0f, s2 = 0.0f;
#pragma unroll
    for (int c = 0; c < 3; c++) {
        v[c] = *(const float4*)(xr + c * 256 + l * 4);
        s  += v[c].x + v[c].y + v[c].z + v[c].w;
        s2 += v[c].x * v[c].x + v[c].y * v[c].y + v[c].z * v[c].z + v[c].w * v[c].w;
    }
#pragma unroll
    for (int off = 32; off; off >>= 1) { s += __shfl_xor(s, off); s2 += __shfl_xor(s2, off); }
    float mean = s * (1.0f / DIM);
    float inv = rsqrtf(s2 * (1.0f / DIM) - mean * mean + 1e-6f);
    ushort* orow = out + (size_t)row * out_stride;
#pragma unroll
    for (int c = 0; c < 3; c++) {
        float4 gg = *(const float4*)(g + c * 256 + l * 4);
        float4 bb = *(const float4*)(bta + c * 256 + l * 4);
        ushort4 o4;
        o4.x = f2bf((v[c].x - mean) * inv * gg.x + bb.x);
        o4.y = f2bf((v[c].y - mean) * inv * gg.y + bb.y);
        o4.z = f2bf((v[c].z - mean) * inv * gg.z + bb.z);
        o4.w = f2bf((v[c].w - mean) * inv * gg.w + bb.w);
        *(ushort4*)(orow + c * 256 + l * 4) = o4;
    }
}

// ---------------------------------------------------------------------------
// Bounded transpose (pre-loop: patch_w, head_w). in KxN -> out NxK bf16.
// ---------------------------------------------------------------------------
__global__ __launch_bounds__(256) void transpose_bf16_kernel(const float* __restrict__ in,
                                                             ushort* __restrict__ out,
                                                             int K, int N) {
    __shared__ float tile[32][33];
    int n0 = blockIdx.x * 32, k0 = blockIdx.y * 32;
    int tx = threadIdx.x;
    int ty = threadIdx.y;
    for (int r = ty; r < 32; r += 8) {
        int k = k0 + r, n = n0 + tx;
        tile[r][tx] = (k < K && n < N) ? in[(size_t)k * N + n] : 0.0f;
    }
    __syncthreads();
    for (int r = ty; r < 32; r += 8) {
        int n = n0 + r, k = k0 + tx;
        if (n < N && k < K) out[(size_t)n * K + k] = f2bf(tile[tx][r]);
    }
}

// ---------------------------------------------------------------------------
// Batched per-layer transpose of the 4 weight mats (all dims %32==0).
// tiles: qkv 72x24=1728 | proj 24x24=576 | fc1 96x24=2304 | fc2 24x96=2304
// ---------------------------------------------------------------------------
__global__ __launch_bounds__(256) void transpose4_kernel(
    const float* __restrict__ w0, const float* __restrict__ w1,
    const float* __restrict__ w2, const float* __restrict__ w3,
    ushort* __restrict__ o0, ushort* __restrict__ o1,
    ushort* __restrict__ o2, ushort* __restrict__ o3) {
    __shared__ float tile[32][33];
    int bid = blockIdx.x;
    const float* in; ushort* out; int K, N, nx, tl;
    if (bid < 1728)      { in = w0; out = o0; K = 768;  N = 2304; nx = 72; tl = bid; }
    else if (bid < 2304) { in = w1; out = o1; K = 768;  N = 768;  nx = 24; tl = bid - 1728; }
    else if (bid < 4608) { in = w2; out = o2; K = 768;  N = 3072; nx = 96; tl = bid - 2304; }
    else                 { in = w3; out = o3; K = 3072; N = 768;  nx = 24; tl = bid - 4608; }
    int n0 = (tl % nx) * 32, k0 = (tl / nx) * 32;
    int tx = threadIdx.x, ty = threadIdx.y;
    for (int r = ty; r < 32; r += 8)
        tile[r][tx] = in[(size_t)(k0 + r) * N + n0 + tx];
    __syncthreads();
    for (int r = ty; r < 32; r += 8)
        out[(size_t)(n0 + r) * K + k0 + tx] = f2bf(tile[tx][r]);
}

// ---------------------------------------------------------------------------
// bf16 MFMA GEMM: BMx128x64 tiles (BM=128 or 64), 4 waves, 16x16x32 MFMA.
// XOR-swizzled LDS chunks (conflict-free ds_read_b128), GROUP_M=8 block
// swizzle for L2 locality. Wt is NxK (row n = col n of W).
// ---------------------------------------------------------------------------
template <int BM, int GELU, int RES, int WF32, int WBF16>
__global__ __launch_bounds__(256) void gemm_bf16_mfma(
    const ushort* __restrict__ A, const ushort* __restrict__ Wt,
    const float* __restrict__ bias, const float* __restrict__ res,
    float* __restrict__ Cf, ushort* __restrict__ Cb,
    int M, int N, int K) {
    constexpr int WN = (BM == 128) ? 2 : 4;   // waves along N
    constexpr int FN = (BM == 128) ? 4 : 2;   // 16-col frags per wave
    constexpr int AROWS = BM / 4;             // A rows staged per wave
    __shared__ short Asm[BM * 64];
    __shared__ short Bsm[128 * 64];
    const int tid = threadIdx.x;
    const int w = tid >> 6, lane = tid & 63;
    const int wm = w / WN, wn = w % WN;

    // GROUP_M=8 swizzled block mapping
    int gX = gridDim.x, gY = gridDim.y;
    int pid = blockIdx.y * gX + blockIdx.x;
    int width = 8 * gX;
    int group = pid / width;
    int first = group * 8;
    int gsz = min(gY - first, 8);
    int by = first + (pid % gsz);
    int bx = (pid % width) / gsz;
    const int m0 = by * BM, n0 = bx * 128;

    floatx4 acc[4][FN] = {};

    // staging: lane -> (row-in-8 = lane>>3, slot = lane&7), global chunk = slot^row
    const int ro = lane >> 3;
    const int sl = lane & 7;
    const int gch = sl ^ ro;
    const ushort* aptr[BM / 32];
    short* alds[BM / 32];
#pragma unroll
    for (int i = 0; i < BM / 32; i++) {
        int r = w * AROWS + i * 8 + ro;
        int gr = min(m0 + r, M - 1);
        aptr[i] = A + (size_t)gr * K + gch * 8;
        alds[i] = Asm + (w * AROWS + i * 8) * 64;
    }
    const ushort* bptr[4];
    short* blds[4];
#pragma unroll
    for (int i = 0; i < 4; i++) {
        int r = w * 32 + i * 8 + ro;
        int gr = min(n0 + r, N - 1);
        bptr[i] = Wt + (size_t)gr * K + gch * 8;
        blds[i] = Bsm + (w * 32 + i * 8) * 64;
    }

    const int fr = lane & 15, quad = lane >> 4;

    for (int k0 = 0; k0 < K; k0 += 64) {
#pragma unroll
        for (int i = 0; i < BM / 32; i++) async_copy16(aptr[i] + k0, alds[i]);
#pragma unroll
        for (int i = 0; i < 4; i++) async_copy16(bptr[i] + k0, blds[i]);
        __syncthreads();
#pragma unroll
        for (int ks = 0; ks < 2; ks++) {
            int soff = (((ks * 4 + quad) ^ (fr & 7)) * 8);
            short8 af[4], bf[FN];
#pragma unroll
            for (int mt = 0; mt < 4; mt++)
                af[mt] = *(const short8*)&Asm[(wm * 64 + mt * 16 + fr) * 64 + soff];
#pragma unroll
            for (int nt = 0; nt < FN; nt++)
                bf[nt] = *(const short8*)&Bsm[(wn * (16 * FN) + nt * 16 + fr) * 64 + soff];
#pragma unroll
            for (int mt = 0; mt < 4; mt++)
#pragma unroll
                for (int nt = 0; nt < FN; nt++)
                    acc[mt][nt] = __builtin_amdgcn_mfma_f32_16x16x32_bf16(af[mt], bf[nt], acc[mt][nt], 0, 0, 0);
        }
        __syncthreads();
    }

#pragma unroll
    for (int nt = 0; nt < FN; nt++) {
        int col = n0 + wn * (16 * FN) + nt * 16 + fr;
        if (col >= N) continue;
        float bv = bias[col];
#pragma unroll
        for (int mt = 0; mt < 4; mt++) {
            int rbase = m0 + wm * 64 + mt * 16 + quad * 4;
#pragma unroll
            for (int r = 0; r < 4; r++) {
                int row = rbase + r;
                if (row >= M) continue;
                float v = acc[mt][nt][r] + bv;
                if (GELU) v = 0.5f * v * (1.0f + erff(v * 0.70710678118654752f));
                if (RES) v += res[(size_t)row * N + col];
                if (WF32) Cf[(size_t)row * N + col] = v;
                if (WBF16) Cb[(size_t)row * N + col] = f2bf(v);
            }
        }
    }
}

// ---------------------------------------------------------------------------
// MFMA attention (round-3 version, unchanged).
// ---------------------------------------------------------------------------
__global__ __launch_bounds__(256, 2) void attn_kernel(const ushort* __restrict__ qkvb,
                                                      const float* __restrict__ mask,
                                                      ushort* __restrict__ o) {
    const int h = blockIdx.x, b = blockIdx.y;
    const int tid = threadIdx.x;
    __shared__ ushort Vfrag[7 * 4 * 64 * 8];
    __shared__ ushort Pfrag[4 * 7 * 64 * 8];

    {
        uint4 z = {0, 0, 0, 0};
        uint4* v4 = (uint4*)Vfrag;
        uint4* p4 = (uint4*)Pfrag;
        for (int i = tid; i < 1792; i += 256) { v4[i] = z; p4[i] = z; }
    }
    __syncthreads();

    for (int pass = 0; pass < 25; pass++) {
        int j = pass * 8 + (tid >> 5);
        if (j <= 196) {
            int d0 = (tid & 31) * 2;
            unsigned int val = *(const unsigned int*)(qkvb + ((size_t)(b * N_TOK + j) * 3 + 2) * DIM + h * HD + d0);
            int kt = j >> 5, dt = d0 >> 4;
            int lane = ((j & 31) >> 3) * 16 + (d0 & 15);
            int jj = j & 7;
            int base = (kt * 4 + dt) * 512 + lane * 8 + jj;
            Vfrag[base] = (ushort)(val & 0xffffu);
            Vfrag[base + 8] = (ushort)(val >> 16);
        }
    }
    __syncthreads();

    const int w = tid >> 6, l = tid & 63;
    const int q = l >> 4, fr = l & 15;
    ushort* Pw = Pfrag + w * 3584;
    const float scale = 0.125f;

    for (int qt = w; qt < 13; qt += 4) {
        int qrow = min(qt * 16 + fr, 196);
        const ushort* qptr = qkvb + ((size_t)(b * N_TOK + qrow) * 3 + 0) * DIM + h * HD + q * 8;
        short8 aq0 = *(const short8*)qptr;
        short8 aq1 = *(const short8*)(qptr + 32);

        floatx4 sacc[13];
#pragma unroll
        for (int nt = 0; nt < 13; nt++) {
            int krow = min(nt * 16 + fr, 196);
            const ushort* kptr = qkvb + ((size_t)(b * N_TOK + krow) * 3 + 1) * DIM + h * HD + q * 8;
            short8 kb0 = *(const short8*)kptr;
            short8 kb1 = *(const short8*)(kptr + 32);
            floatx4 acc = {};
            acc = __builtin_amdgcn_mfma_f32_16x16x32_bf16(aq0, kb0, acc, 0, 0, 0);
            acc = __builtin_amdgcn_mfma_f32_16x16x32_bf16(aq1, kb1, acc, 0, 0, 0);
            sacc[nt] = acc;
        }

        float mx[4] = {-1e30f, -1e30f, -1e30f, -1e30f};
#pragma unroll
        for (int nt = 0; nt < 13; nt++) {
            int jcol = nt * 16 + fr;
#pragma unroll
            for (int r = 0; r < 4; r++) {
                int irow = min(qt * 16 + q * 4 + r, 196);
                float s;
                if (jcol <= 196) s = sacc[nt][r] * scale * mask[irow * N_TOK + jcol];
                else s = -1e30f;
                sacc[nt][r] = s;
                mx[r] = fmaxf(mx[r], s);
            }
        }
#pragma unroll
        for (int r = 0; r < 4; r++) {
            mx[r] = fmaxf(mx[r], __shfl_xor(mx[r], 1));
            mx[r] = fmaxf(mx[r], __shfl_xor(mx[r], 2));
            mx[r] = fmaxf(mx[r], __shfl_xor(mx[r], 4));
            mx[r] = fmaxf(mx[r], __shfl_xor(mx[r], 8));
        }

        float sum[4] = {0, 0, 0, 0};
#pragma unroll
        for (int nt = 0; nt < 13; nt++) {
            int kt = nt >> 1;
            int lpbase = ((nt & 1) * 2 + ((l & 8) >> 3)) * 16;
#pragma unroll
            for (int r = 0; r < 4; r++) {
                float e = __expf(sacc[nt][r] - mx[r]);
                sum[r] += e;
                int lp = (q * 4 + r) + lpbase;
                Pw[kt * 512 + lp * 8 + (l & 7)] = f2bf(e);
            }
        }
#pragma unroll
        for (int r = 0; r < 4; r++) {
            sum[r] += __shfl_xor(sum[r], 1);
            sum[r] += __shfl_xor(sum[r], 2);
            sum[r] += __shfl_xor(sum[r], 4);
            sum[r] += __shfl_xor(sum[r], 8);
        }

        floatx4 oacc[4] = {};
#pragma unroll
        for (int kt = 0; kt < 7; kt++) {
            short8 pa = *(const short8*)&Pw[kt * 512 + l * 8];
#pragma unroll
            for (int dt = 0; dt < 4; dt++) {
                short8 vb = *(const short8*)&Vfrag[(kt * 4 + dt) * 512 + l * 8];
                oacc[dt] = __builtin_amdgcn_mfma_f32_16x16x32_bf16(pa, vb, oacc[dt], 0, 0, 0);
            }
        }

        float inv[4];
#pragma unroll
        for (int r = 0; r < 4; r++) inv[r] = 1.0f / sum[r];
#pragma unroll
        for (int dt = 0; dt < 4; dt++) {
#pragma unroll
            for (int r = 0; r < 4; r++) {
                int irow = qt * 16 + q * 4 + r;
                if (irow <= 196)
                    o[((size_t)(b * N_TOK + irow)) * DIM + h * HD + dt * 16 + fr] = f2bf(oacc[dt][r] * inv[r]);
            }
        }
    }
}

// ---------------------------------------------------------------------------
extern "C" void kernel_launch(void* const* d_in, const int* in_sizes, int n_in,
                              void* d_out, int out_size, void* d_ws, size_t ws_size,
                              hipStream_t stream) {
    const float* x       = (const float*)d_in[0];
    const float* cp_mask = (const float*)d_in[1];
    const float* patch_w = (const float*)d_in[2];
    const float* patch_b = (const float*)d_in[3];
    const float* cls_tok = (const float*)d_in[4];
    const float* pos_emb = (const float*)d_in[5];
    const float* ln1_g   = (const float*)d_in[6];
    const float* ln1_b   = (const float*)d_in[7];
    const float* qkv_w   = (const float*)d_in[8];
    const float* qkv_b   = (const float*)d_in[9];
    const float* proj_w  = (const float*)d_in[10];
    const float* proj_b  = (const float*)d_in[11];
    const float* ln2_g   = (const float*)d_in[12];
    const float* ln2_b   = (const float*)d_in[13];
    const float* fc1_w   = (const float*)d_in[14];
    const float* fc1_b   = (const float*)d_in[15];
    const float* fc2_w   = (const float*)d_in[16];
    const float* fc2_b   = (const float*)d_in[17];
    const float* normf_g = (const float*)d_in[18];
    const float* normf_b = (const float*)d_in[19];
    const float* head_w  = (const float*)d_in[20];
    const float* head_b  = (const float*)d_in[21];
    float* out = (float*)d_out;

    const int M = BATCH * N_TOK;  // 6304
    char* p = (char*)d_ws;
    auto alloc = [&](size_t bytes) { char* r = p; p += (bytes + 255) & ~(size_t)255; return r; };
    float*  t         = (float*)alloc((size_t)M * DIM * 4);
    float*  patchout  = (float*)alloc((size_t)BATCH * NPATCH * DIM * 4);
    ushort* h_bf      = (ushort*)alloc((size_t)M * DIM * 2);
    ushort* qkv_bf    = (ushort*)alloc((size_t)M * 3 * DIM * 2);
    ushort* o_bf      = (ushort*)alloc((size_t)M * DIM * 2);
    ushort* hidden_bf = (ushort*)alloc((size_t)M * MLP_DIM * 2);
    ushort* pooled_bf = (ushort*)alloc((size_t)BATCH * DIM * 2);
    ushort* wq_t      = (ushort*)alloc((size_t)3 * DIM * DIM * 2);
    ushort* wp_t      = (ushort*)alloc((size_t)DIM * DIM * 2);
    ushort* w1_t      = (ushort*)alloc((size_t)MLP_DIM * DIM * 2);
    ushort* w2_t      = (ushort*)alloc((size_t)DIM * MLP_DIM * 2);
    ushort* wpt       = (ushort*)alloc((size_t)DIM * DIM * 2);
    ushort* wht       = (ushort*)alloc((size_t)NCLS * DIM * 2);

    const dim3 tb(32, 8);

    transpose_bf16_kernel<<<dim3(24, 24), tb, 0, stream>>>(patch_w, wpt, DIM, DIM);
    transpose_bf16_kernel<<<dim3(32, 24), tb, 0, stream>>>(head_w, wht, DIM, NCLS);
    {
        int total = BATCH * NPATCH * DIM;
        im2col_kernel<<<(total + 255) / 256, 256, 0, stream>>>(x, h_bf);
        gemm_bf16_mfma<64, 0, 0, 1, 0><<<dim3(6, 98), 256, 0, stream>>>(
            h_bf, wpt, patch_b, nullptr, patchout, nullptr, BATCH * NPATCH, DIM, DIM);
        int total2 = M * DIM;
        assemble_kernel<<<(total2 + 255) / 256, 256, 0, stream>>>(patchout, cls_tok, pos_emb, t);
    }

    for (int l = 0; l < DEPTH; l++) {
        transpose4_kernel<<<6912, tb, 0, stream>>>(
            qkv_w + (size_t)l * DIM * 3 * DIM, proj_w + (size_t)l * DIM * DIM,
            fc1_w + (size_t)l * DIM * MLP_DIM, fc2_w + (size_t)l * MLP_DIM * DIM,
            wq_t, wp_t, w1_t, w2_t);

        lnw_kernel<<<M / 4, 256, 0, stream>>>(t, ln1_g + l * DIM, ln1_b + l * DIM, h_bf, M, DIM, DIM);

        gemm_bf16_mfma<128, 0, 0, 0, 1><<<dim3(18, 50), 256, 0, stream>>>(
            h_bf, wq_t, qkv_b + (size_t)l * 3 * DIM, nullptr, nullptr, qkv_bf, M, 3 * DIM, DIM);

        attn_kernel<<<dim3(HEADS, BATCH), 256, 0, stream>>>(qkv_bf, cp_mask, o_bf);

        gemm_bf16_mfma<64, 0, 1, 1, 0><<<dim3(6, 99), 256, 0, stream>>>(
            o_bf, wp_t, proj_b + (size_t)l * DIM, t, t, nullptr, M, DIM, DIM);

        lnw_kernel<<<M / 4, 256, 0, stream>>>(t, ln2_g + l * DIM, ln2_b + l * DIM, h_bf, M, DIM, DIM);

        gemm_bf16_mfma<128, 1, 0, 0, 1><<<dim3(24, 50), 256, 0, stream>>>(
            h_bf, w1_t, fc1_b + (size_t)l * MLP_DIM, nullptr, nullptr, hidden_bf, M, MLP_DIM, DIM);

        gemm_bf16_mfma<64, 0, 1, 1, 0><<<dim3(6, 99), 256, 0, stream>>>(
            hidden_bf, w2_t, fc2_b + (size_t)l * DIM, t, t, nullptr, M, DIM, MLP_DIM);
    }

    lnw_kernel<<<8, 256, 0, stream>>>(t, normf_g, normf_b, pooled_bf, BATCH, N_TOK * DIM, DIM);
    gemm_bf16_mfma<64, 0, 0, 1, 0><<<dim3(8, 1), 256, 0, stream>>>(
        pooled_bf, wht, head_b, nullptr, out, nullptr, BATCH, NCLS, DIM);
}